// Round 10
// baseline (85.767 us; speedup 1.0000x reference)
//
#include <hip/hip_runtime.h>

#define NW 10

typedef float v2f __attribute__((ext_vector_type(2)));
typedef float v4f __attribute__((ext_vector_type(4)));

// DPP: quad_perm xor1=0xB1, xor2=0x4E; row_ror:8 (xor8 within 16) = 0x128
template<int CTRL>
__device__ __forceinline__ float fdpp(float v) {
    return __int_as_float(__builtin_amdgcn_mov_dpp(__float_as_int(v), CTRL, 0xF, 0xF, true));
}
// ds_swizzle BitMode: xor4=0x101F, xor16=0x401F (final reduction only)
template<int PAT>
__device__ __forceinline__ float fswz(float v) {
    return __int_as_float(__builtin_amdgcn_ds_swizzle(__float_as_int(v), PAT));
}

// ---- Layouts ----
// C : r0=s0 r1=s1 | l0=s2 l1=s3 l2=s4 l3=s5 l4=s6 l5=s7 | W0=s8 W1=s9
// L1: r0=s8 r1=s9 | l0=s4 l1=s6 l2=s2 l3=s7 l4=s3 l5=s5 | W0=s0 W1=s1
// Packed address of thread slot: a = W<<8 | lane<<2 | r.  For layout C, the
// state at address a is simply s = a.  For L1 it is sL1(W,lane,r):
__device__ __forceinline__ int sL1(int W, int lane, int r) {
    return ((r & 1) << 8) | (((r >> 1) & 1) << 9)
         | ((lane & 1) << 4) | (((lane >> 1) & 1) << 6) | (((lane >> 2) & 1) << 2)
         | (((lane >> 3) & 1) << 7) | (((lane >> 4) & 1) << 3) | (((lane >> 5) & 1) << 5)
         | ((W & 1) << 0) | (((W >> 1) & 1) << 1);
}
// LDS bank swizzle on packed v2f addresses: phi(a) = a ^ (a6<<3) ^ (a4<<1).
// Verified: b128 own-writes conflict-free; retile & perm gathers 2-way (free).
__device__ __forceinline__ int phiA(int a) { return a ^ ((a & 0x50) >> 3); }

// ---------------- precompute: 14 diag tables [c,s,-s,c] + 80 RY (cos,sin) ----------------
// d<3: rz0(k=d+1) [C] ; d<7: rz2(k=d-3) [L1] ; d<11: rz3(k=d-7) [C] ; d<14: rz5(k=d-11) [L1]
// Entry j holds the phase of the state stored at packed address j in that layout.
__global__ void precompute_kernel(const float* __restrict__ params, float4* __restrict__ tab4) {
    const int d = blockIdx.x;
    const int j = threadIdx.x;
    if (d < 14) {
        int k, row; bool L1;
        if (d < 3)       { k = d + 1;  row = 0; L1 = false; }
        else if (d < 7)  { k = d - 3;  row = 2; L1 = true;  }
        else if (d < 11) { k = d - 7;  row = 3; L1 = false; }
        else             { k = d - 11; row = 5; L1 = true;  }
        const float* th = params + (k * 6 + row) * NW;
        const int s = L1 ? sL1(j >> 8, (j >> 2) & 63, j & 3) : j;
        float ang = 0.f;
#pragma unroll
        for (int w = 0; w < NW; ++w)
            ang += th[w] * (((s >> (9 - w)) & 1) ? 0.5f : -0.5f);
        float sn, cs;
        __sincosf(ang, &sn, &cs);
        tab4[d * 1024 + j] = make_float4(cs, sn, -sn, cs);
    } else if (j < 80) {
        const int ry = j / NW, w = j % NW;
        const int k = ry >> 1, i = ry & 1;
        const float* th = params + (k * 6 + (i ? 4 : 1)) * NW;
        float sn, cs;
        __sincosf(0.5f * th[w], &sn, &cs);
        float2* ryt = (float2*)(tab4 + 14 * 1024);
        ryt[j] = make_float2(cs, sn);
    }
}

// ---------------- main kernel ----------------
__global__ __launch_bounds__(256, 4) void qsim_kernel(const float* __restrict__ x,
                                                      const v4f* __restrict__ tab4,
                                                      float* __restrict__ out) {
    __shared__ __align__(16) v2f buf[2][1024];
    __shared__ float sred[4][NW];

    const int t     = threadIdx.x;
    const int W     = t >> 6;
    const int lane  = t & 63;
    const int b     = blockIdx.x;
    const float2* ry_tab = (const float2*)(tab4 + 14 * 1024);

    v2f st[4];
#pragma unroll
    for (int r = 0; r < 4; ++r) st[r] = (v2f){0.f, 0.f};
    if (t == 0) st[0].x = 1.f;

    const int l0 = lane & 1, l1 = (lane >> 1) & 1, l2 = (lane >> 2) & 1,
              l3 = (lane >> 3) & 1, l4 = (lane >> 4) & 1, l5 = (lane >> 5) & 1;
    const int W0 = W & 1, W1 = (W >> 1) & 1;

    // Own-slot b128 write: v4f index for (st0,st1); partner ^1 holds (st2,st3).
    const int wb4 = (t << 1) ^ (l4 << 2) ^ l2;
    // Retile gather (read C-data while taking L1 role): addr = phi(sL1(W,lane,0)) + r<<8
    const int rgA2 = phiA(sL1(W, lane, 0));
    // Perm gather (read L1-data, restore C): addressL1(q(sC(W,lane,0))), phi'd;
    // r-masks {0,0x103,0x300,0x203} are phi-transparent.
    const int abase = (W0 ^ W1) | (W1 << 1) | ((l2 ^ l3) << 2) | ((l4 ^ l5) << 3)
                    | ((l0 ^ l1) << 4) | ((l5 ^ W0) << 5) | ((l1 ^ l2) << 6)
                    | ((l3 ^ l4) << 7) | (l0 << 9);
    const int gP2 = phiA(abase);

    // x-phase e^{iA_x(s)} (C layout), reused for the 3 encoding diagonals
    const float* xb = x + b * NW;
    v2f xp[4];
    {
        float xv[NW];
#pragma unroll
        for (int w = 0; w < NW; ++w) xv[w] = xb[w];
        float A = 0.f;
#pragma unroll
        for (int w = 0; w < NW; ++w) A += xv[w];
        float hi = -0.5f * A;
        if (W & 2) hi += xv[0];
        if (W & 1) hi += xv[1];
#pragma unroll
        for (int j = 0; j < 6; ++j)
            hi += ((lane >> j) & 1) ? xv[7 - j] : 0.f;
        float lo[4];
        lo[0] = 0.f;   lo[1] = xv[9];
        lo[2] = xv[8]; lo[3] = xv[8] + xv[9];
#pragma unroll
        for (int r = 0; r < 4; ++r) {
            float sn, cs;
            __sincosf(hi + lo[r], &sn, &cs);
            xp[r] = (v2f){cs, sn};
        }
    }

    int bs = 0;
    v4f tq[4];   // prefetched diagonal entries

    auto pre = [&](int d) {
        const v4f* tb = tab4 + (d << 10) + (t << 2);
#pragma unroll
        for (int r = 0; r < 4; ++r) tq[r] = tb[r];
    };
    auto apply_t = [&]() {
#pragma unroll
        for (int r = 0; r < 4; ++r)
            st[r] = st[r].x * tq[r].xy + st[r].y * tq[r].zw;
    };
    auto apply_tx = [&]() {
#pragma unroll
        for (int r = 0; r < 4; ++r) {
            const v2f c = xp[r].x * tq[r].xy + xp[r].y * tq[r].zw;
            const v2f cq = (v2f){-c.y, c.x};
            st[r] = st[r].x * c + st[r].y * cq;
        }
    };

    auto bfly_local = [&](float2 cw, int m) {
#pragma unroll
        for (int r = 0; r < 4; ++r) {
            if (!(r & m)) {
                const int r2 = r | m;
                const v2f a = st[r];
                st[r]  = cw.x * a - cw.y * st[r2];
                st[r2] = cw.y * a + cw.x * st[r2];
            }
        }
    };

    auto lds_write_own = [&](v2f* B) {
        v4f* B4 = (v4f*)B;
        B4[wb4]     = (v4f){st[0].x, st[0].y, st[1].x, st[1].y};
        B4[wb4 ^ 1] = (v4f){st[2].x, st[2].y, st[3].x, st[3].y};
    };

    auto ry = [&](int ridx) {
        const float2* rt = ry_tab + ridx * NW;
        bfly_local(rt[9], 1);
        bfly_local(rt[8], 2);
        {   const float2 cw = rt[7]; const float ss = (lane & 1) ? cw.y : -cw.y;
#pragma unroll
            for (int r = 0; r < 4; ++r) {
                v2f p; p.x = fdpp<0xB1>(st[r].x); p.y = fdpp<0xB1>(st[r].y);
                st[r] = cw.x * st[r] + ss * p;
            }
        }
        {   const float2 cw = rt[6]; const float ss = (lane & 2) ? cw.y : -cw.y;
#pragma unroll
            for (int r = 0; r < 4; ++r) {
                v2f p; p.x = fdpp<0x4E>(st[r].x); p.y = fdpp<0x4E>(st[r].y);
                st[r] = cw.x * st[r] + ss * p;
            }
        }
        {   const float2 cw = rt[4]; const float ss = (lane & 8) ? cw.y : -cw.y;
#pragma unroll
            for (int r = 0; r < 4; ++r) {
                v2f p; p.x = fdpp<0x128>(st[r].x); p.y = fdpp<0x128>(st[r].y);
                st[r] = cw.x * st[r] + ss * p;
            }
        }
        // retile C -> L1 (b128 writes, one barrier)
        {
            v2f* B = buf[bs]; bs ^= 1;
            lds_write_own(B);
            __syncthreads();
#pragma unroll
            for (int r = 0; r < 4; ++r)
                st[r] = B[rgA2 + (r << 8)];
        }
        bfly_local(rt[1], 1);      // s8
        bfly_local(rt[0], 2);      // s9
        {   const float2 cw = rt[5]; const float ss = (lane & 1) ? cw.y : -cw.y;   // s4
#pragma unroll
            for (int r = 0; r < 4; ++r) {
                v2f p; p.x = fdpp<0xB1>(st[r].x); p.y = fdpp<0xB1>(st[r].y);
                st[r] = cw.x * st[r] + ss * p;
            }
        }
        {   const float2 cw = rt[3]; const float ss = (lane & 2) ? cw.y : -cw.y;   // s6
#pragma unroll
            for (int r = 0; r < 4; ++r) {
                v2f p; p.x = fdpp<0x4E>(st[r].x); p.y = fdpp<0x4E>(st[r].y);
                st[r] = cw.x * st[r] + ss * p;
            }
        }
        {   const float2 cw = rt[2]; const float ss = (lane & 8) ? cw.y : -cw.y;   // s7
#pragma unroll
            for (int r = 0; r < 4; ++r) {
                v2f p; p.x = fdpp<0x128>(st[r].x); p.y = fdpp<0x128>(st[r].y);
                st[r] = cw.x * st[r] + ss * p;
            }
        }
    };

    auto perm = [&]() {
        v2f* B = buf[bs]; bs ^= 1;
        lds_write_own(B);
        __syncthreads();
        constexpr int xq[4] = {0, 0x103, 0x300, 0x203};
#pragma unroll
        for (int r = 0; r < 4; ++r)
            st[r] = B[gP2 ^ xq[r]];
    };

#pragma unroll 1
    for (int k = 0; k < 4; ++k) {
        if (k > 0) apply_tx();          // enc(prev)+rz0(k); k=0 rz0 = global phase
        pre(3 + k);
        ry(2 * k);                      // barrier inside, ends L1
        apply_t();                      // rz2, L1
        pre(7 + k);
        perm();                         // barrier, -> C
        apply_t();                      // rz3, C
        if (k < 3) pre(11 + k);
        ry(2 * k + 1);                  // barrier, ends L1
        if (k < 3) { apply_t(); pre(k); perm(); }   // rz5 (L1); prefetch txdiag; -> C
        // k==3: rz5 is a pure phase (dropped) and the final perm is folded
        // into the epilogue signs via sigma^{-1} (suffix parities).
    }

    // ---- epilogue in L1 layout; last perm folded in.
    // s_{9-w} of the true final index = suffix parity of held-state bits u.
    // r-part: wires 1..9 -> (-1)^{r0^r1} => D; wire 0 -> (-1)^{r0} => E.
    float pr[4];
#pragma unroll
    for (int r = 0; r < 4; ++r) pr[r] = st[r].x * st[r].x + st[r].y * st[r].y;
    const float D = pr[0] - pr[1] - pr[2] + pr[3];
    const float E = pr[0] - pr[1] + pr[2] - pr[3];
    // suffix parities over (u7..u0) = (l3,l1,l5,l0,l4,l2,W1,W0)
    const int g2 = l3;
    const int g3 = g2 ^ l1;
    const int g4 = g3 ^ l5;
    const int g5 = g4 ^ l0;
    const int g6 = g5 ^ l4;
    const int g7 = g6 ^ l2;
    const int g8 = g7 ^ W1;
    const int g9 = g8 ^ W0;

    float acc[NW];
    acc[0] = g9 ? -E : E;
    acc[1] = D;
    acc[2] = g2 ? -D : D;
    acc[3] = g3 ? -D : D;
    acc[4] = g4 ? -D : D;
    acc[5] = g5 ? -D : D;
    acc[6] = g6 ? -D : D;
    acc[7] = g7 ? -D : D;
    acc[8] = g8 ? -D : D;
    acc[9] = g9 ? -D : D;

#pragma unroll
    for (int w = 0; w < NW; ++w) {
        float a = acc[w];
        a += fdpp<0xB1>(a);
        a += fdpp<0x4E>(a);
        a += fswz<0x101F>(a);
        a += fdpp<0x128>(a);
        a += fswz<0x401F>(a);
        a += __shfl_xor(a, 32, 64);
        acc[w] = a;
    }
    if (lane == 0) {
#pragma unroll
        for (int w = 0; w < NW; ++w) sred[W][w] = acc[w];
    }
    __syncthreads();
    if (t < NW) out[b * NW + t] = sred[0][t] + sred[1][t] + sred[2][t] + sred[3][t];
}

extern "C" void kernel_launch(void* const* d_in, const int* in_sizes, int n_in,
                              void* d_out, int out_size, void* d_ws, size_t ws_size,
                              hipStream_t stream) {
    const float* x      = (const float*)d_in[0];   // (2048, 10)
    const float* params = (const float*)d_in[1];   // (4, 6, 10)
    float* out          = (float*)d_out;           // (1, 2048, 10)
    float4* tab4        = (float4*)d_ws;           // 14*1024 float4 + 80 float2 = 225 KB
    (void)in_sizes; (void)n_in; (void)out_size; (void)ws_size;
    precompute_kernel<<<15, 1024, 0, stream>>>(params, tab4);
    qsim_kernel<<<2048, 256, 0, stream>>>(x, (const v4f*)tab4, out);
}

// Round 11
// 80.126 us; speedup vs baseline: 1.0704x; 1.0704x over previous
//
#include <hip/hip_runtime.h>

#define NW 10

typedef float v2f __attribute__((ext_vector_type(2)));
typedef float v4f __attribute__((ext_vector_type(4)));

// DPP: quad_perm xor1=0xB1, xor2=0x4E; row_ror:8 (xor8 within 16) = 0x128
template<int CTRL>
__device__ __forceinline__ float fdpp(float v) {
    return __int_as_float(__builtin_amdgcn_mov_dpp(__float_as_int(v), CTRL, 0xF, 0xF, true));
}
// ds_swizzle BitMode: xor4=0x101F, xor16=0x401F (final reduction only)
template<int PAT>
__device__ __forceinline__ float fswz(float v) {
    return __int_as_float(__builtin_amdgcn_ds_swizzle(__float_as_int(v), PAT));
}

// ---- Layouts ----
// C : r0=s0 r1=s1 | l0=s2 l1=s3 l2=s4 l3=s5 l4=s6 l5=s7 | W0=s8 W1=s9
// L1: r0=s8 r1=s9 | l0=s4 l1=s6 l2=s2 l3=s7 l4=s3 l5=s5 | W0=s0 W1=s1
// Element index e = lane | r<<6 | W<<8 in the layout's own coords.
// LDS bank swizzle: phi(e) = e ^ (e4<<3) ^ (e5<<1)
__device__ __forceinline__ int phi(int e) {
    return e ^ ((e & 0x10) >> 1) ^ ((e & 0x20) >> 4);
}

// -------- precompute: 7 folded diag tables [c,s,-s,c] + 80 RY (cos,sin) --------
// Fold rule: D2 ⊙ P(D1 ⊙ s)[u] = (D2[u]·D1[q(u)])·s[q(u)],  q(s)=s^(s>>1)^((s&1)*0x300).
// d<4 : T1[k=d]   = rz3_k(s) · rz2_k(q(s))          (applied post-perm, C layout)
// d<7 : T2[k=d-4] = rz0_{k+1}(s) · rz5_k(q(s))      (applied post-perm with x-phase)
// Entry j: lane=j&63, r=(j>>6)&3, W=j>>8, C-state s = W<<8 | lane<<2 | r.
__global__ void precompute_kernel(const float* __restrict__ params, float4* __restrict__ tab4) {
    const int d = blockIdx.x;
    const int j = threadIdx.x;
    if (d < 7) {
        const int W = j >> 8, lane = j & 63, r = (j >> 6) & 3;
        const int s = (W << 8) | (lane << 2) | r;
        const int q = s ^ (s >> 1) ^ ((s & 1) * 0x300);
        const float* thA;   // phase at s (post-perm diag)
        const float* thB;   // phase at q (pre-perm diag)
        if (d < 4) {
            thA = params + (d * 6 + 3) * NW;          // rz3 of block d
            thB = params + (d * 6 + 2) * NW;          // rz2 of block d
        } else {
            const int k = d - 4;
            thA = params + ((k + 1) * 6 + 0) * NW;    // rz0 of block k+1
            thB = params + (k * 6 + 5) * NW;          // rz5 of block k
        }
        float ang = 0.f;
#pragma unroll
        for (int w = 0; w < NW; ++w) {
            ang += thA[w] * (((s >> (9 - w)) & 1) ? 0.5f : -0.5f);
            ang += thB[w] * (((q >> (9 - w)) & 1) ? 0.5f : -0.5f);
        }
        float sn, cs;
        __sincosf(ang, &sn, &cs);
        tab4[d * 1024 + j] = make_float4(cs, sn, -sn, cs);
    } else if (j < 80) {
        const int ry = j / NW, w = j % NW;
        const int k = ry >> 1, i = ry & 1;
        const float* th = params + (k * 6 + (i ? 4 : 1)) * NW;
        float sn, cs;
        __sincosf(0.5f * th[w], &sn, &cs);
        float2* ryt = (float2*)(tab4 + 7 * 1024);
        ryt[j] = make_float2(cs, sn);
    }
}

// ---------------- main kernel ----------------
__global__ __launch_bounds__(256, 4) void qsim_kernel(const float* __restrict__ x,
                                                      const v4f* __restrict__ tab4,
                                                      float* __restrict__ out) {
    __shared__ v2f buf[2][1024];
    __shared__ float sred[4][NW];

    const int t     = threadIdx.x;
    const int W     = t >> 6;
    const int lane  = t & 63;
    const int b     = blockIdx.x;
    const int ebase = lane | (W << 8);
    const float2* ry_tab = (const float2*)(tab4 + 7 * 1024);

    v2f st[4];
#pragma unroll
    for (int r = 0; r < 4; ++r) st[r] = (v2f){0.f, 0.f};
    if (t == 0) st[0].x = 1.f;

    const int wbase = phi(ebase);
    const int l0 = lane & 1, l1 = (lane >> 1) & 1, l2 = (lane >> 2) & 1,
              l3 = (lane >> 3) & 1, l4 = (lane >> 4) & 1, l5 = (lane >> 5) & 1;
    const int W0 = W & 1, W1 = (W >> 1) & 1;
    // Retile gather base: eC(sL1(W,lane,0)); offsets r<<8 (phi-safe)
    const int riA0 = l2 | (l4 << 1) | (l0 << 2) | (l5 << 3) | (l1 << 4) | (l3 << 5) | (W << 6);
    const int rgA  = phi(riA0);
    // Perm gather: geidx[r] = g0 ^ {0,0x1C0,0x300,0x2C0}[r]; phi folded into g0
    const int g0 = (l2 ^ l3) | ((l4 ^ l5) << 1) | ((l0 ^ l1) << 2) | ((l5 ^ W0) << 3)
                 | ((l1 ^ l2) << 4) | ((l3 ^ l4) << 5)
                 | ((W0 ^ W1) << 6) | (W1 << 7) | (l0 << 9);
    const int gP = phi(g0);

    // x-phase e^{iA_x(s)} (C layout) as v2f [xc, xs]
    const float* xb = x + b * NW;
    v2f xp[4];
    {
        float xv[NW];
#pragma unroll
        for (int w = 0; w < NW; ++w) xv[w] = xb[w];
        float A = 0.f;
#pragma unroll
        for (int w = 0; w < NW; ++w) A += xv[w];
        float hi = -0.5f * A;
        if (W & 2) hi += xv[0];
        if (W & 1) hi += xv[1];
#pragma unroll
        for (int j = 0; j < 6; ++j)
            hi += ((lane >> j) & 1) ? xv[7 - j] : 0.f;
        float lo[4];
        lo[0] = 0.f;   lo[1] = xv[9];
        lo[2] = xv[8]; lo[3] = xv[8] + xv[9];
#pragma unroll
        for (int r = 0; r < 4; ++r) {
            float sn, cs;
            __sincosf(hi + lo[r], &sn, &cs);
            xp[r] = (v2f){cs, sn};
        }
    }

    int bs = 0;
    v4f tq[4];   // prefetched folded-diag entries (loads in flight across barriers)

    auto pre = [&](int d) {
        const v4f* tb = tab4 + (d << 10) + ebase;
#pragma unroll
        for (int r = 0; r < 4; ++r) tq[r] = tb[r << 6];
    };
    auto apply_t = [&]() {
#pragma unroll
        for (int r = 0; r < 4; ++r)
            st[r] = st[r].x * tq[r].xy + st[r].y * tq[r].zw;
    };
    auto apply_tx = [&]() {
#pragma unroll
        for (int r = 0; r < 4; ++r) {
            const v2f c = xp[r].x * tq[r].xy + xp[r].y * tq[r].zw;
            const v2f cq = (v2f){-c.y, c.x};
            st[r] = st[r].x * c + st[r].y * cq;
        }
    };

    auto bfly_local = [&](float2 cw, int m) {
#pragma unroll
        for (int r = 0; r < 4; ++r) {
            if (!(r & m)) {
                const int r2 = r | m;
                const v2f a = st[r];
                st[r]  = cw.x * a - cw.y * st[r2];
                st[r2] = cw.y * a + cw.x * st[r2];
            }
        }
    };

    // ry: phase A in C (wires 9,8 local; 7,6,4 DPP), retile C->L1, phase B
    // (wires 1,0 local; 5,3,2 DPP). Ends in L1.
    auto ry = [&](int ridx) {
        const float2* rt = ry_tab + ridx * NW;
        bfly_local(rt[9], 1);
        bfly_local(rt[8], 2);
        {   const float2 cw = rt[7]; const float ss = (lane & 1) ? cw.y : -cw.y;
#pragma unroll
            for (int r = 0; r < 4; ++r) {
                v2f p; p.x = fdpp<0xB1>(st[r].x); p.y = fdpp<0xB1>(st[r].y);
                st[r] = cw.x * st[r] + ss * p;
            }
        }
        {   const float2 cw = rt[6]; const float ss = (lane & 2) ? cw.y : -cw.y;
#pragma unroll
            for (int r = 0; r < 4; ++r) {
                v2f p; p.x = fdpp<0x4E>(st[r].x); p.y = fdpp<0x4E>(st[r].y);
                st[r] = cw.x * st[r] + ss * p;
            }
        }
        {   const float2 cw = rt[4]; const float ss = (lane & 8) ? cw.y : -cw.y;
#pragma unroll
            for (int r = 0; r < 4; ++r) {
                v2f p; p.x = fdpp<0x128>(st[r].x); p.y = fdpp<0x128>(st[r].y);
                st[r] = cw.x * st[r] + ss * p;
            }
        }
        // retile C -> L1 (swizzled, one barrier)
        {
            v2f* B = buf[bs]; bs ^= 1;
#pragma unroll
            for (int r = 0; r < 4; ++r)
                B[wbase + (r << 6)] = st[r];
            __syncthreads();
#pragma unroll
            for (int r = 0; r < 4; ++r)
                st[r] = B[rgA + (r << 8)];
        }
        bfly_local(rt[1], 1);      // s8
        bfly_local(rt[0], 2);      // s9
        {   const float2 cw = rt[5]; const float ss = (lane & 1) ? cw.y : -cw.y;   // s4
#pragma unroll
            for (int r = 0; r < 4; ++r) {
                v2f p; p.x = fdpp<0xB1>(st[r].x); p.y = fdpp<0xB1>(st[r].y);
                st[r] = cw.x * st[r] + ss * p;
            }
        }
        {   const float2 cw = rt[3]; const float ss = (lane & 2) ? cw.y : -cw.y;   // s6
#pragma unroll
            for (int r = 0; r < 4; ++r) {
                v2f p; p.x = fdpp<0x4E>(st[r].x); p.y = fdpp<0x4E>(st[r].y);
                st[r] = cw.x * st[r] + ss * p;
            }
        }
        {   const float2 cw = rt[2]; const float ss = (lane & 8) ? cw.y : -cw.y;   // s7
#pragma unroll
            for (int r = 0; r < 4; ++r) {
                v2f p; p.x = fdpp<0x128>(st[r].x); p.y = fdpp<0x128>(st[r].y);
                st[r] = cw.x * st[r] + ss * p;
            }
        }
    };

    auto perm = [&]() {
        v2f* B = buf[bs]; bs ^= 1;
#pragma unroll
        for (int r = 0; r < 4; ++r)
            B[wbase + (r << 6)] = st[r];
        __syncthreads();
        constexpr int xc[4] = {0, 0x1C0, 0x300, 0x2C0};
#pragma unroll
        for (int r = 0; r < 4; ++r)
            st[r] = B[gP ^ xc[r]];
    };

    // Block k: [rz0+enc applied as T2 of prev iter] ry(2k) | perm+T1[k] (rz2,rz3 folded)
    //          | ry(2k+1) | perm+T2[k] (rz5, rz0(k+1), enc folded; k=3: all pure phase)
#pragma unroll 1
    for (int k = 0; k < 4; ++k) {
        pre(k);                          // T1[k]
        ry(2 * k);                       // barrier inside, ends L1
        perm();                          // barrier, -> C
        apply_t();                       // rz2∘q · rz3
        if (k < 3) pre(4 + k);           // T2[k]
        ry(2 * k + 1);                   // barrier, ends L1
        perm();                          // barrier, -> C
        if (k < 3) apply_tx();           // rz5∘q · rz0(k+1) · enc(x)
    }

    // out[b][w] = sum_s |st|^2 * (1-2*bit_{9-w}(s))   (state in C)
    float pr[4];
#pragma unroll
    for (int r = 0; r < 4; ++r) pr[r] = st[r].x * st[r].x + st[r].y * st[r].y;
    float S = 0.f;
#pragma unroll
    for (int r = 0; r < 4; ++r) S += pr[r];

    float acc[NW];
    acc[0] = (W & 2) ? -S : S;                 // s9
    acc[1] = (W & 1) ? -S : S;                 // s8
#pragma unroll
    for (int w = 2; w <= 7; ++w) {             // lane bit j = 7-w
        const int j = 7 - w;
        acc[w] = ((lane >> j) & 1) ? -S : S;
    }
    {
        float t8 = 0.f, t9 = 0.f;
#pragma unroll
        for (int r = 0; r < 4; ++r) {
            t8 += (r & 2) ? -pr[r] : pr[r];
            t9 += (r & 1) ? -pr[r] : pr[r];
        }
        acc[8] = t8; acc[9] = t9;
    }
#pragma unroll
    for (int w = 0; w < NW; ++w) {
        float a = acc[w];
        a += fdpp<0xB1>(a);
        a += fdpp<0x4E>(a);
        a += fswz<0x101F>(a);
        a += fdpp<0x128>(a);
        a += fswz<0x401F>(a);
        a += __shfl_xor(a, 32, 64);
        acc[w] = a;
    }
    if (lane == 0) {
#pragma unroll
        for (int w = 0; w < NW; ++w) sred[W][w] = acc[w];
    }
    __syncthreads();
    if (t < NW) out[b * NW + t] = sred[0][t] + sred[1][t] + sred[2][t] + sred[3][t];
}

extern "C" void kernel_launch(void* const* d_in, const int* in_sizes, int n_in,
                              void* d_out, int out_size, void* d_ws, size_t ws_size,
                              hipStream_t stream) {
    const float* x      = (const float*)d_in[0];   // (2048, 10)
    const float* params = (const float*)d_in[1];   // (4, 6, 10)
    float* out          = (float*)d_out;           // (1, 2048, 10)
    float4* tab4        = (float4*)d_ws;           // 7*1024 float4 + 80 float2 = 113 KB
    (void)in_sizes; (void)n_in; (void)out_size; (void)ws_size;
    precompute_kernel<<<8, 1024, 0, stream>>>(params, tab4);
    qsim_kernel<<<2048, 256, 0, stream>>>(x, (const v4f*)tab4, out);
}

// Round 12
// 79.933 us; speedup vs baseline: 1.0730x; 1.0024x over previous
//
#include <hip/hip_runtime.h>

#define NW 10

typedef float v2f __attribute__((ext_vector_type(2)));
typedef float v4f __attribute__((ext_vector_type(4)));

// DPP: quad_perm xor1=0xB1, xor2=0x4E; row_ror:8 (xor8 within 16) = 0x128
template<int CTRL>
__device__ __forceinline__ float fdpp(float v) {
    return __int_as_float(__builtin_amdgcn_mov_dpp(__float_as_int(v), CTRL, 0xF, 0xF, true));
}
// ds_swizzle BitMode: xor4=0x101F, xor16=0x401F (final reduction only)
template<int PAT>
__device__ __forceinline__ float fswz(float v) {
    return __int_as_float(__builtin_amdgcn_ds_swizzle(__float_as_int(v), PAT));
}

// ---- Layouts ----
// C : r0=s0 r1=s1 | l0=s2 l1=s3 l2=s4 l3=s5 l4=s6 l5=s7 | W0=s8 W1=s9
// L1: r0=s8 r1=s9 | l0=s4 l1=s6 l2=s2 l3=s7 l4=s3 l5=s5 | W0=s0 W1=s1
// Element index e = lane | r<<6 | W<<8 in the layout's own coords.
// LDS bank swizzle: phi(e) = e ^ (e4<<3) ^ (e5<<1)
__device__ __forceinline__ int phi(int e) {
    return e ^ ((e & 0x10) >> 1) ^ ((e & 0x20) >> 4);
}

// -------- precompute: 7 folded diag tables [c,s,-s,c] + 80 RY (cos,sin) --------
// Fold rule: D2 ⊙ P(D1 ⊙ s)[u] = (D2[u]·D1[q(u)])·s[q(u)],  q(s)=s^(s>>1)^((s&1)*0x300).
// d<4 : T1[k=d]   = rz3_k(s) · rz2_k(q(s))          (applied post-perm, C layout)
// d<7 : T2[k=d-4] = rz0_{k+1}(s) · rz5_k(q(s))      (applied post-perm with x-phase)
__global__ void precompute_kernel(const float* __restrict__ params, float4* __restrict__ tab4) {
    const int d = blockIdx.x;
    const int j = threadIdx.x;
    if (d < 7) {
        const int W = j >> 8, lane = j & 63, r = (j >> 6) & 3;
        const int s = (W << 8) | (lane << 2) | r;
        const int q = s ^ (s >> 1) ^ ((s & 1) * 0x300);
        const float* thA;
        const float* thB;
        if (d < 4) {
            thA = params + (d * 6 + 3) * NW;          // rz3 of block d
            thB = params + (d * 6 + 2) * NW;          // rz2 of block d
        } else {
            const int k = d - 4;
            thA = params + ((k + 1) * 6 + 0) * NW;    // rz0 of block k+1
            thB = params + (k * 6 + 5) * NW;          // rz5 of block k
        }
        float ang = 0.f;
#pragma unroll
        for (int w = 0; w < NW; ++w) {
            ang += thA[w] * (((s >> (9 - w)) & 1) ? 0.5f : -0.5f);
            ang += thB[w] * (((q >> (9 - w)) & 1) ? 0.5f : -0.5f);
        }
        float sn, cs;
        __sincosf(ang, &sn, &cs);
        tab4[d * 1024 + j] = make_float4(cs, sn, -sn, cs);
    } else if (j < 80) {
        const int ry = j / NW, w = j % NW;
        const int k = ry >> 1, i = ry & 1;
        const float* th = params + (k * 6 + (i ? 4 : 1)) * NW;
        float sn, cs;
        __sincosf(0.5f * th[w], &sn, &cs);
        float2* ryt = (float2*)(tab4 + 7 * 1024);
        ryt[j] = make_float2(cs, sn);
    }
}

// ---------------- main kernel ----------------
__global__ __launch_bounds__(256, 4) void qsim_kernel(const float* __restrict__ x,
                                                      const v4f* __restrict__ tab4,
                                                      float* __restrict__ out) {
    __shared__ v2f buf[2][1024];
    __shared__ float sred[4][NW];

    const int t     = threadIdx.x;
    const int W     = t >> 6;
    const int lane  = t & 63;
    const int b     = blockIdx.x;
    const int ebase = lane | (W << 8);
    const float2* ry_tab = (const float2*)(tab4 + 7 * 1024);

    v2f st[4];

    const int wbase = phi(ebase);
    const int l0 = lane & 1, l1 = (lane >> 1) & 1, l2 = (lane >> 2) & 1,
              l3 = (lane >> 3) & 1, l4 = (lane >> 4) & 1, l5 = (lane >> 5) & 1;
    const int W0 = W & 1, W1 = (W >> 1) & 1;
    // Retile gather base: eC(sL1(W,lane,0)); offsets r<<8 (phi-safe)
    const int riA0 = l2 | (l4 << 1) | (l0 << 2) | (l5 << 3) | (l1 << 4) | (l3 << 5) | (W << 6);
    const int rgA  = phi(riA0);
    // Perm gather: geidx[r] = g0 ^ {0,0x1C0,0x300,0x2C0}[r]; phi folded into g0
    const int g0 = (l2 ^ l3) | ((l4 ^ l5) << 1) | ((l0 ^ l1) << 2) | ((l5 ^ W0) << 3)
                 | ((l1 ^ l2) << 4) | ((l3 ^ l4) << 5)
                 | ((W0 ^ W1) << 6) | (W1 << 7) | (l0 << 9);
    const int gP = phi(g0);

    // x-phase e^{iA_x(s)} (C layout) as v2f [xc, xs]
    const float* xb = x + b * NW;
    v2f xp[4];
    {
        float xv[NW];
#pragma unroll
        for (int w = 0; w < NW; ++w) xv[w] = xb[w];
        float A = 0.f;
#pragma unroll
        for (int w = 0; w < NW; ++w) A += xv[w];
        float hi = -0.5f * A;
        if (W & 2) hi += xv[0];
        if (W & 1) hi += xv[1];
#pragma unroll
        for (int j = 0; j < 6; ++j)
            hi += ((lane >> j) & 1) ? xv[7 - j] : 0.f;
        float lo[4];
        lo[0] = 0.f;   lo[1] = xv[9];
        lo[2] = xv[8]; lo[3] = xv[8] + xv[9];
#pragma unroll
        for (int r = 0; r < 4; ++r) {
            float sn, cs;
            __sincosf(hi + lo[r], &sn, &cs);
            xp[r] = (v2f){cs, sn};
        }
    }

    int bs = 0;
    v4f tq[4];   // prefetched folded-diag entries

    auto pre = [&](int d) {
        const v4f* tb = tab4 + (d << 10) + ebase;
#pragma unroll
        for (int r = 0; r < 4; ++r) tq[r] = tb[r << 6];
    };
    auto apply_t = [&]() {
#pragma unroll
        for (int r = 0; r < 4; ++r)
            st[r] = st[r].x * tq[r].xy + st[r].y * tq[r].zw;
    };
    auto apply_tx = [&]() {
#pragma unroll
        for (int r = 0; r < 4; ++r) {
            const v2f c = xp[r].x * tq[r].xy + xp[r].y * tq[r].zw;
            const v2f cq = (v2f){-c.y, c.x};
            st[r] = st[r].x * c + st[r].y * cq;
        }
    };

    // Analytic init: state after (dropped global-phase rz0(0)) + ry(0) on |0> is
    // the real product state amp(s) = prod_w (bit_{9-w}(s) ? sin_w : cos_w),
    // written directly in L1 coords (s8=r0, s9=r1, s4=l0, s6=l1, s2=l2, s7=l3,
    // s3=l4, s5=l5, s0=W0, s1=W1; bit b <-> wire 9-b).
    auto init_L1 = [&]() {
        const float2* rt = ry_tab;   // ridx 0
        float hi = (l0 ? rt[5].y : rt[5].x);
        hi *= (l1 ? rt[3].y : rt[3].x);
        hi *= (l2 ? rt[7].y : rt[7].x);
        hi *= (l3 ? rt[2].y : rt[2].x);
        hi *= (l4 ? rt[6].y : rt[6].x);
        hi *= (l5 ? rt[4].y : rt[4].x);
        hi *= (W0 ? rt[9].y : rt[9].x);
        hi *= (W1 ? rt[8].y : rt[8].x);
        const float c1 = rt[1].x, s1 = rt[1].y, c0 = rt[0].x, s0_ = rt[0].y;
        st[0] = (v2f){hi * c1 * c0, 0.f};
        st[1] = (v2f){hi * s1 * c0, 0.f};
        st[2] = (v2f){hi * c1 * s0_, 0.f};
        st[3] = (v2f){hi * s1 * s0_, 0.f};
    };

    auto bfly_local = [&](float2 cw, int m) {
#pragma unroll
        for (int r = 0; r < 4; ++r) {
            if (!(r & m)) {
                const int r2 = r | m;
                const v2f a = st[r];
                st[r]  = cw.x * a - cw.y * st[r2];
                st[r2] = cw.y * a + cw.x * st[r2];
            }
        }
    };

    // ry: phase A in C (wires 9,8 local; 7,6,4 DPP), retile C->L1, phase B
    // (wires 1,0 local; 5,3,2 DPP). Ends in L1.
    auto ry = [&](int ridx) {
        const float2* rt = ry_tab + ridx * NW;
        bfly_local(rt[9], 1);
        bfly_local(rt[8], 2);
        {   const float2 cw = rt[7]; const float ss = (lane & 1) ? cw.y : -cw.y;
#pragma unroll
            for (int r = 0; r < 4; ++r) {
                v2f p; p.x = fdpp<0xB1>(st[r].x); p.y = fdpp<0xB1>(st[r].y);
                st[r] = cw.x * st[r] + ss * p;
            }
        }
        {   const float2 cw = rt[6]; const float ss = (lane & 2) ? cw.y : -cw.y;
#pragma unroll
            for (int r = 0; r < 4; ++r) {
                v2f p; p.x = fdpp<0x4E>(st[r].x); p.y = fdpp<0x4E>(st[r].y);
                st[r] = cw.x * st[r] + ss * p;
            }
        }
        {   const float2 cw = rt[4]; const float ss = (lane & 8) ? cw.y : -cw.y;
#pragma unroll
            for (int r = 0; r < 4; ++r) {
                v2f p; p.x = fdpp<0x128>(st[r].x); p.y = fdpp<0x128>(st[r].y);
                st[r] = cw.x * st[r] + ss * p;
            }
        }
        // retile C -> L1 (swizzled, one barrier)
        {
            v2f* B = buf[bs]; bs ^= 1;
#pragma unroll
            for (int r = 0; r < 4; ++r)
                B[wbase + (r << 6)] = st[r];
            __syncthreads();
#pragma unroll
            for (int r = 0; r < 4; ++r)
                st[r] = B[rgA + (r << 8)];
        }
        bfly_local(rt[1], 1);      // s8
        bfly_local(rt[0], 2);      // s9
        {   const float2 cw = rt[5]; const float ss = (lane & 1) ? cw.y : -cw.y;   // s4
#pragma unroll
            for (int r = 0; r < 4; ++r) {
                v2f p; p.x = fdpp<0xB1>(st[r].x); p.y = fdpp<0xB1>(st[r].y);
                st[r] = cw.x * st[r] + ss * p;
            }
        }
        {   const float2 cw = rt[3]; const float ss = (lane & 2) ? cw.y : -cw.y;   // s6
#pragma unroll
            for (int r = 0; r < 4; ++r) {
                v2f p; p.x = fdpp<0x4E>(st[r].x); p.y = fdpp<0x4E>(st[r].y);
                st[r] = cw.x * st[r] + ss * p;
            }
        }
        {   const float2 cw = rt[2]; const float ss = (lane & 8) ? cw.y : -cw.y;   // s7
#pragma unroll
            for (int r = 0; r < 4; ++r) {
                v2f p; p.x = fdpp<0x128>(st[r].x); p.y = fdpp<0x128>(st[r].y);
                st[r] = cw.x * st[r] + ss * p;
            }
        }
    };

    auto perm = [&]() {
        v2f* B = buf[bs]; bs ^= 1;
#pragma unroll
        for (int r = 0; r < 4; ++r)
            B[wbase + (r << 6)] = st[r];
        __syncthreads();
        constexpr int xc[4] = {0, 0x1C0, 0x300, 0x2C0};
#pragma unroll
        for (int r = 0; r < 4; ++r)
            st[r] = B[gP ^ xc[r]];
    };

#pragma unroll 1
    for (int k = 0; k < 4; ++k) {
        pre(k);                          // T1[k]
        if (k == 0) init_L1();           // analytic |0> -> ry(0) product state (L1)
        else        ry(2 * k);           // barrier inside, ends L1
        perm();                          // barrier, -> C
        apply_t();                       // rz2∘q · rz3
        if (k < 3) pre(4 + k);           // T2[k]
        ry(2 * k + 1);                   // barrier, ends L1
        if (k < 3) {
            perm();                      // barrier, -> C
            apply_tx();                  // rz5∘q · rz0(k+1) · enc(x)
        }
        // k==3: rz5 is a pure phase (dropped); final perm folded into epilogue signs.
    }

    // ---- epilogue in L1 layout, final perm folded via sigma^{-1} suffix parities.
    // r-part: wires 1..9 -> (-1)^{r0^r1} => D; wire 0 -> (-1)^{r0} => E.
    float pr[4];
#pragma unroll
    for (int r = 0; r < 4; ++r) pr[r] = st[r].x * st[r].x + st[r].y * st[r].y;
    const float D = pr[0] - pr[1] - pr[2] + pr[3];
    const float E = pr[0] - pr[1] + pr[2] - pr[3];
    // suffix parities over (u7..u0) = (l3,l1,l5,l0,l4,l2,W1,W0)
    const int g2 = l3;
    const int g3 = g2 ^ l1;
    const int g4 = g3 ^ l5;
    const int g5 = g4 ^ l0;
    const int g6 = g5 ^ l4;
    const int g7 = g6 ^ l2;
    const int g8 = g7 ^ W1;
    const int g9 = g8 ^ W0;

    float acc[NW];
    acc[0] = g9 ? -E : E;
    acc[1] = D;
    acc[2] = g2 ? -D : D;
    acc[3] = g3 ? -D : D;
    acc[4] = g4 ? -D : D;
    acc[5] = g5 ? -D : D;
    acc[6] = g6 ? -D : D;
    acc[7] = g7 ? -D : D;
    acc[8] = g8 ? -D : D;
    acc[9] = g9 ? -D : D;

#pragma unroll
    for (int w = 0; w < NW; ++w) {
        float a = acc[w];
        a += fdpp<0xB1>(a);
        a += fdpp<0x4E>(a);
        a += fswz<0x101F>(a);
        a += fdpp<0x128>(a);
        a += fswz<0x401F>(a);
        a += __shfl_xor(a, 32, 64);
        acc[w] = a;
    }
    if (lane == 0) {
#pragma unroll
        for (int w = 0; w < NW; ++w) sred[W][w] = acc[w];
    }
    __syncthreads();
    if (t < NW) out[b * NW + t] = sred[0][t] + sred[1][t] + sred[2][t] + sred[3][t];
}

extern "C" void kernel_launch(void* const* d_in, const int* in_sizes, int n_in,
                              void* d_out, int out_size, void* d_ws, size_t ws_size,
                              hipStream_t stream) {
    const float* x      = (const float*)d_in[0];   // (2048, 10)
    const float* params = (const float*)d_in[1];   // (4, 6, 10)
    float* out          = (float*)d_out;           // (1, 2048, 10)
    float4* tab4        = (float4*)d_ws;           // 7*1024 float4 + 80 float2 = 113 KB
    (void)in_sizes; (void)n_in; (void)out_size; (void)ws_size;
    precompute_kernel<<<8, 1024, 0, stream>>>(params, tab4);
    qsim_kernel<<<2048, 256, 0, stream>>>(x, (const v4f*)tab4, out);
}